// Round 8
// baseline (229.956 us; speedup 1.0000x reference)
//
#include <hip/hip_runtime.h>

typedef _Float16 f16;
typedef _Float16 f16x2 __attribute__((ext_vector_type(2)));
typedef _Float16 f16x4 __attribute__((ext_vector_type(4)));
typedef _Float16 f16x8 __attribute__((ext_vector_type(8)));
typedef float    f32x16 __attribute__((ext_vector_type(16)));

#define NB   8
#define TE   2048
#define TD   2048
#define DIM  256
#define NBTD (NB * TD)
#define LOG2E 1.44269504088896340736f

#define AS1(p) ((const __attribute__((address_space(1))) void*)(p))
#define AS3(p) ((__attribute__((address_space(3))) void*)(p))
#define MFMA32(a,b,c) __builtin_amdgcn_mfma_f32_32x32x16_f16((a),(b),(c),0,0,0)
#define SHUF8(x,y) __builtin_shufflevector((x),(y),0,1,2,3,4,5,6,7)

__device__ __forceinline__ unsigned lds_u32(void* p) {
    return (unsigned)(size_t)((__attribute__((address_space(3))) void*)p);
}
// ds_read_b64_tr_b16 (validated r4/r5): per-lane 8B payload at its own addr; in-group
// permutation delivers out[l][j] = block[row j][col l&15] for a 4x16 row-major 128B
// block when per-lane addr = block_base + (l&15)*8.
__device__ __forceinline__ f16x4 tr_rd0(unsigned a) {
    f16x4 r;
    asm volatile("ds_read_b64_tr_b16 %0, %1" : "=v"(r) : "v"(a));
    return r;
}
__device__ __forceinline__ f16x4 tr_rd1(unsigned a) {   // +2048 = next e4 subtile row
    f16x4 r;
    asm volatile("ds_read_b64_tr_b16 %0, %1 offset:2048" : "=v"(r) : "v"(a));
    return r;
}

// ---------------- prep: enc fp32 -> f16, same layout ----------------
__global__ __launch_bounds__(256) void prep_kernel(const float* __restrict__ enc,
                                                   f16* __restrict__ ench) {
    size_t i = ((size_t)blockIdx.x * 256 + threadIdx.x) * 8;
    float4 v0 = *(const float4*)(enc + i);
    float4 v1 = *(const float4*)(enc + i + 4);
    f16x8 o;
    o[0]=(f16)v0.x; o[1]=(f16)v0.y; o[2]=(f16)v0.z; o[3]=(f16)v0.w;
    o[4]=(f16)v1.x; o[5]=(f16)v1.y; o[6]=(f16)v1.z; o[7]=(f16)v1.w;
    *(f16x8*)(ench + i) = o;
}

// ---------------- fused attention + split-k merge tail ----------------
// Core = round-5 kernel (best measured: wave-decoupled, 32x32x16 MFMA, 1 barrier/iter,
// 4 waves x 32 t, nsplit=4 over e, 512 blocks = 2/CU) -- UNCHANGED.
// New: no combine kernel. Partials: z<2 -> ctxp f16 (normalized); z=2 -> out[0:256) f32;
// z=3 -> out[256:512) f32 (parked, read by merger before overwrite). m/l -> ml f16x2
// (m snapped to f16 in-loop, storage exact). Merge: the 4 blocks of group (b,xb) share
// cnt[b*16+xb]; each does threadfence -> syncthreads -> tid0 atomicAdd; the one seeing
// old==3 acquires and merges 128 rows x 256 d (combine's exact math). Group blocks share
// fid%8 -> same-XCD L2 for the partial round-trip; protocol is device-scope correct
// regardless of placement (G16).
__global__ __launch_bounds__(256, 2) void attn_kernel(
        const float* __restrict__ dec32,
        const f16*  __restrict__ enc_h,
        f16*   __restrict__ ctxp,
        f16x2* __restrict__ ml,
        float* __restrict__ out,
        unsigned* __restrict__ cnt) {
    __shared__ __align__(16) char lds[43008];
    __shared__ int do_merge;
    const int tid  = threadIdx.x;
    const int lane = tid & 63;
    const int wv   = tid >> 6;
    const int t5   = lane & 31;   // this lane's t-column (within wave tile)
    const int hi   = lane >> 5;

    const int fid = blockIdx.x + 16 * (blockIdx.y + 8 * blockIdx.z);
    const int b    = fid & 7;
    const int rest = fid >> 3;
    const int xb   = rest & 15;
    const int z    = rest >> 4;           // 0..3
    const int t0   = xb * 128 + wv * 32;
    const int tile0 = z * 16;             // 16 e-tiles of 32 per split
    const int ITERS = 16;

    const char* encb = (const char*)(enc_h + (size_t)b * TE * DIM);

    // staging map (proven r2-r5): chunk c = i*256 + wv*64 + lane (16B), inverse subtile map
    const int c0  = wv * 64 + lane;
    const int e_l = ((c0 >> 7) << 2) | ((c0 >> 1) & 3);
    const int d_l = (((c0 >> 3) & 15) << 4) | ((c0 & 1) << 3);
    const int stage_goff = e_l * (DIM * 2) + d_l * 2;
    char* stage_dst = lds + wv * 1024;

    // QK A-read (row e = lane&31, d-window ks*16 + hi*8, f16x8):
    const int qk_base = ((lane & 31) >> 2) * 2048 + (lane & 3) * 32 + hi * 16;
    // PV tr read: subtile(e4 = ks*4 + hi*2, d16 = dm*2 + ((lane>>4)&1)), payload + (l&15)*8
    const unsigned tr_base = (unsigned)(hi * 4096 + ((lane >> 4) & 1) * 128 + (lane & 15) * 8);
    const unsigned lds_base = lds_u32(lds);
    char* pb = lds + 32768 + wv * 2560;   // per-wave P scratch: [t32][e32] f16, pitch 80

    // Q fragments: B[k = ks*16 + hi*8 + j][n = t5]  (16 ks x f16x8 = 64 VGPR)
    f16x8 qf[16];
    {
        const float* qrow = dec32 + ((size_t)b * TD + t0 + t5) * DIM + hi * 8;
        #pragma unroll
        for (int ks = 0; ks < 16; ks++) {
            float4 u = *(const float4*)(qrow + ks * 16);
            float4 v = *(const float4*)(qrow + ks * 16 + 4);
            f16x8 o;
            o[0]=(f16)u.x; o[1]=(f16)u.y; o[2]=(f16)u.z; o[3]=(f16)u.w;
            o[4]=(f16)v.x; o[5]=(f16)v.y; o[6]=(f16)v.z; o[7]=(f16)v.w;
            qf[ks] = o;
        }
    }

    { // stage tile0 -> buf0
        const char* s = encb + (size_t)tile0 * 16384 + stage_goff;
        #pragma unroll
        for (int i = 0; i < 4; i++)
            __builtin_amdgcn_global_load_lds(AS1(s + i * 4096), AS3(stage_dst + i * 4096), 16, 0, 0);
    }

    float m_ = -INFINITY, l_ = 0.f;
    f32x16 ctx[8];
    #pragma unroll
    for (int dm = 0; dm < 8; dm++)
        #pragma unroll
        for (int r = 0; r < 16; r++) ctx[dm][r] = 0.f;

    __syncthreads();   // tile0 staged & drained

    for (int it = 0; it < ITERS; ++it) {
        const int nat = (it & 1) << 14;
        // stage next tile early: drained at THIS iter's end barrier (full window)
        if (it + 1 < ITERS) {
            const char* s = encb + (size_t)(tile0 + it + 1) * 16384 + stage_goff;
            char* dd = lds + (((it + 1) & 1) << 14) + wv * 1024;
            #pragma unroll
            for (int i = 0; i < 4; i++)
                __builtin_amdgcn_global_load_lds(AS1(s + i * 4096), AS3(dd + i * 4096), 16, 0, 0);
        }
        // ---- QK: St[e32][t32], 16 k-steps of 32x32x16 ----
        f32x16 st;
        #pragma unroll
        for (int r = 0; r < 16; r++) st[r] = 0.f;
        const char* natp = lds + nat + qk_base;
        #pragma unroll
        for (int ks = 0; ks < 16; ks++) {
            f16x8 af = *(const f16x8*)(natp + ks * 128);
            st = MFMA32(af, qf[ks], st);
        }
        // ---- softmax (lane-local t-column; e rows split lane vs lane^32) ----
        float x0 = fmaxf(fmaxf(st[0], st[1]),  fmaxf(st[2], st[3]));
        float x1 = fmaxf(fmaxf(st[4], st[5]),  fmaxf(st[6], st[7]));
        float x2 = fmaxf(fmaxf(st[8], st[9]),  fmaxf(st[10], st[11]));
        float x3 = fmaxf(fmaxf(st[12], st[13]), fmaxf(st[14], st[15]));
        float mx = fmaxf(fmaxf(x0, x1), fmaxf(x2, x3));
        mx = fmaxf(mx, __shfl_xor(mx, 32, 64));
        float ms = (float)(f16)fmaxf(m_, mx);   // snap to f16 (>= m_, >= mx - ulp/2)
        float al = __builtin_amdgcn_exp2f((m_ - ms) * LOG2E);
        bool bump = ms > m_;
        m_ = ms;
        float ssum = 0.f;
        #pragma unroll
        for (int g = 0; g < 4; g++) {           // e-group: e = 8g + 4hi + r
            f16x4 pv;
            #pragma unroll
            for (int r = 0; r < 4; r++) {
                float p = __builtin_amdgcn_exp2f((st[4 * g + r] - ms) * LOG2E);
                pv[r] = (f16)p;
                ssum += (float)pv[r];
            }
            *(f16x4*)(pb + t5 * 80 + g * 16 + hi * 8) = pv;   // P[t][e], pitch 80
        }
        ssum += __shfl_xor(ssum, 32, 64);
        l_ = l_ * al + ssum;
        if (__any(bump)) {
            #pragma unroll
            for (int dm = 0; dm < 8; dm++)
                #pragma unroll
                for (int r = 0; r < 16; r++) ctx[dm][r] *= al;
        }
        // ---- PV: ctx[d = dm*32 + row][t32]; A = enc^T tr-reads, B = P (same-wave LDS) ----
        const unsigned trb = lds_base + (unsigned)nat + tr_base;
        #pragma unroll
        for (int ks = 0; ks < 2; ks++) {
            f16x8 pf = *(const f16x8*)(pb + t5 * 80 + ks * 32 + hi * 16);
            const unsigned ab = trb + (unsigned)(ks * 8192);
            f16x4 a0 = tr_rd0(ab);        f16x4 a1 = tr_rd1(ab);
            f16x4 a2 = tr_rd0(ab + 256);  f16x4 a3 = tr_rd1(ab + 256);
            f16x4 a4 = tr_rd0(ab + 512);  f16x4 a5 = tr_rd1(ab + 512);
            f16x4 a6 = tr_rd0(ab + 768);  f16x4 a7 = tr_rd1(ab + 768);
            asm volatile("s_waitcnt lgkmcnt(0)" ::: "memory");
            __builtin_amdgcn_sched_barrier(0);
            ctx[0] = MFMA32(SHUF8(a0, a1), pf, ctx[0]);
            ctx[1] = MFMA32(SHUF8(a2, a3), pf, ctx[1]);
            ctx[2] = MFMA32(SHUF8(a4, a5), pf, ctx[2]);
            ctx[3] = MFMA32(SHUF8(a6, a7), pf, ctx[3]);
            f16x4 b0 = tr_rd0(ab + 1024); f16x4 b1 = tr_rd1(ab + 1024);
            f16x4 b2 = tr_rd0(ab + 1280); f16x4 b3 = tr_rd1(ab + 1280);
            f16x4 b4 = tr_rd0(ab + 1536); f16x4 b5 = tr_rd1(ab + 1536);
            f16x4 b6 = tr_rd0(ab + 1792); f16x4 b7 = tr_rd1(ab + 1792);
            asm volatile("s_waitcnt lgkmcnt(0)" ::: "memory");
            __builtin_amdgcn_sched_barrier(0);
            ctx[4] = MFMA32(SHUF8(b0, b1), pf, ctx[4]);
            ctx[5] = MFMA32(SHUF8(b2, b3), pf, ctx[5]);
            ctx[6] = MFMA32(SHUF8(b4, b5), pf, ctx[6]);
            ctx[7] = MFMA32(SHUF8(b6, b7), pf, ctx[7]);
        }
        __syncthreads();   // NAT dbuf protection + drains staging(it+1) issued a window ago
    }

    // ---- epilogue: normalized partials ----
    const float inv = 1.0f / l_;
    const size_t row = (size_t)b * TD + t0 + t5;
    if (z < 2) {
        f16* cb = ctxp + ((size_t)z * NBTD + row) * DIM;
        #pragma unroll
        for (int dm = 0; dm < 8; dm++)
            #pragma unroll
            for (int g = 0; g < 4; g++) {
                f16x4 cv;
                #pragma unroll
                for (int r = 0; r < 4; r++) cv[r] = (f16)(ctx[dm][4 * g + r] * inv);
                *(f16x4*)(cb + dm * 32 + g * 8 + hi * 4) = cv;   // d = dm*32 + 8g + 4hi + r
            }
    } else {
        float* ob = out + row * 512 + (z == 3 ? 256 : 0);   // park f32 partial in out
        #pragma unroll
        for (int dm = 0; dm < 8; dm++)
            #pragma unroll
            for (int g = 0; g < 4; g++) {
                float4 cv;
                cv.x = ctx[dm][4 * g]     * inv;
                cv.y = ctx[dm][4 * g + 1] * inv;
                cv.z = ctx[dm][4 * g + 2] * inv;
                cv.w = ctx[dm][4 * g + 3] * inv;
                *(float4*)(ob + dm * 32 + g * 8 + hi * 4) = cv;
            }
    }
    if (hi == 0) {
        f16x2 v; v[0] = (f16)m_; v[1] = (f16)l_;   // m_ exactly f16 (snapped)
        ml[(size_t)z * NBTD + row] = v;
    }

    // ---- split-k merge: last block of group (b,xb) combines the 4 partials ----
    __threadfence();                       // release this block's partial stores
    __syncthreads();                       // all threads' fences precede the atomic
    if (tid == 0) {
        unsigned old = atomicAdd(&cnt[b * 16 + xb], 1u);
        do_merge = (old == 3u);
    }
    __syncthreads();
    if (do_merge) {
        __threadfence();                   // acquire: other blocks' stores visible
        const size_t rbase = (size_t)b * TD + xb * 128;
        for (int i = 0; i < 16; i++) {
            int idx2 = i * 256 + tid;
            int tl = idx2 >> 5;            // 0..127
            int dg = (idx2 & 31) * 8;
            size_t trow = rbase + tl;
            float m0[4], l0[4], M = -INFINITY;
            #pragma unroll
            for (int s = 0; s < 4; s++) {
                f16x2 v = ml[(size_t)s * NBTD + trow];
                m0[s] = (float)v[0];
                l0[s] = (float)v[1];
                M = fmaxf(M, m0[s]);
            }
            float L = 0.f, w[4];
            #pragma unroll
            for (int s = 0; s < 4; s++) {
                w[s] = __builtin_amdgcn_exp2f((m0[s] - M) * LOG2E) * l0[s];
                L += w[s];
            }
            float invL = 1.0f / L;
            float acc[8];
            {   // split 0,1: f16 partials in ctxp
                f16x8 v = *(const f16x8*)(ctxp + (size_t)trow * DIM + dg);
                float w0 = w[0] * invL;
                #pragma unroll
                for (int j = 0; j < 8; j++) acc[j] = w0 * (float)v[j];
                f16x8 u = *(const f16x8*)(ctxp + ((size_t)NBTD + trow) * DIM + dg);
                float w1 = w[1] * invL;
                #pragma unroll
                for (int j = 0; j < 8; j++) acc[j] += w1 * (float)u[j];
            }
            float* ob = out + (size_t)trow * 512;
            {   // split 2: parked in out[0:256)
                float4 p0 = *(const float4*)(ob + dg);
                float4 p1 = *(const float4*)(ob + dg + 4);
                float w2 = w[2] * invL;
                acc[0] += w2 * p0.x; acc[1] += w2 * p0.y; acc[2] += w2 * p0.z; acc[3] += w2 * p0.w;
                acc[4] += w2 * p1.x; acc[5] += w2 * p1.y; acc[6] += w2 * p1.z; acc[7] += w2 * p1.w;
            }
            {   // split 3: parked in out[256:512)
                float4 p0 = *(const float4*)(ob + 256 + dg);
                float4 p1 = *(const float4*)(ob + 256 + dg + 4);
                float w3 = w[3] * invL;
                acc[0] += w3 * p0.x; acc[1] += w3 * p0.y; acc[2] += w3 * p0.z; acc[3] += w3 * p0.w;
                acc[4] += w3 * p1.x; acc[5] += w3 * p1.y; acc[6] += w3 * p1.z; acc[7] += w3 * p1.w;
            }
            float4 d0 = *(const float4*)(dec32 + (size_t)trow * DIM + dg);
            float4 d1 = *(const float4*)(dec32 + (size_t)trow * DIM + dg + 4);
            *(float4*)(ob + dg)     = d0;   // overwrite parked s2 with decoder passthrough
            *(float4*)(ob + dg + 4) = d1;
            float4 c0, c1;
            c0.x=acc[0]; c0.y=acc[1]; c0.z=acc[2]; c0.w=acc[3];
            c1.x=acc[4]; c1.y=acc[5]; c1.z=acc[6]; c1.w=acc[7];
            *(float4*)(ob + 256 + dg)     = c0;
            *(float4*)(ob + 256 + dg + 4) = c1;
        }
    }
}

extern "C" void kernel_launch(void* const* d_in, const int* in_sizes, int n_in,
                              void* d_out, int out_size, void* d_ws, size_t ws_size,
                              hipStream_t stream) {
    (void)in_sizes; (void)n_in;
    const float* enc = (const float*)d_in[0];
    const float* dec = (const float*)d_in[1];
    float* out = (float*)d_out;

    const size_t MLB  = (size_t)4 * NBTD * 4;         // 262,144 (f16x2 per split-row)
    const size_t HB   = (size_t)NB * TE * DIM * 2;    // 8,388,608 (ench)
    const size_t C2   = (size_t)2 * NBTD * DIM * 2;   // 16,777,216 (ctxp splits 0,1)
    const size_t CNTB = 512;                          // 128 group counters
    const size_t NEED = MLB + HB + C2 + CNTB;         // 25,428,480 << proven 33.8 MB

    if (ws_size < NEED) {
        hipMemsetAsync(d_out, 0, (size_t)out_size * sizeof(float), stream);
        return;
    }
    f16x2*    ml   = (f16x2*)d_ws;
    f16*      ench = (f16*)((char*)d_ws + MLB);
    f16*      ctxp = (f16*)((char*)d_ws + MLB + HB);
    unsigned* cnt  = (unsigned*)((char*)d_ws + MLB + HB + C2);

    hipMemsetAsync(cnt, 0, CNTB, stream);
    prep_kernel<<<2048, 256, 0, stream>>>(enc, ench);
    attn_kernel<<<dim3(16, 8, 4), 256, 0, stream>>>(dec, ench, ctxp, ml, out, cnt);
}

// Round 9
// 147.404 us; speedup vs baseline: 1.5600x; 1.5600x over previous
//
#include <hip/hip_runtime.h>

typedef _Float16 f16;
typedef _Float16 f16x4 __attribute__((ext_vector_type(4)));
typedef _Float16 f16x8 __attribute__((ext_vector_type(8)));
typedef float    f32x2 __attribute__((ext_vector_type(2)));
typedef float    f32x16 __attribute__((ext_vector_type(16)));
typedef unsigned u32x2 __attribute__((ext_vector_type(2)));

#define NB   8
#define TE   2048
#define TD   2048
#define DIM  256
#define NBTD (NB * TD)
#define LOG2E 1.44269504088896340736f

#define AS1(p) ((const __attribute__((address_space(1))) void*)(p))
#define AS3(p) ((__attribute__((address_space(3))) void*)(p))
#define MFMA32(a,b,c) __builtin_amdgcn_mfma_f32_32x32x16_f16((a),(b),(c),0,0,0)
#define SHUF8(x,y) __builtin_shufflevector((x),(y),0,1,2,3,4,5,6,7)

__device__ __forceinline__ unsigned lds_u32(void* p) {
    return (unsigned)(size_t)((__attribute__((address_space(3))) void*)p);
}
// ds_read_b64_tr_b16 (validated r4/r5): per-lane 8B payload at its own addr; in-group
// permutation delivers out[l][j] = block[row j][col l&15] for a 4x16 row-major 128B
// block when per-lane addr = block_base + (l&15)*8.
__device__ __forceinline__ f16x4 tr_rd0(unsigned a) {
    f16x4 r;
    asm volatile("ds_read_b64_tr_b16 %0, %1" : "=v"(r) : "v"(a));
    return r;
}
__device__ __forceinline__ f16x4 tr_rd1(unsigned a) {   // +2048 = next e4 subtile row
    f16x4 r;
    asm volatile("ds_read_b64_tr_b16 %0, %1 offset:2048" : "=v"(r) : "v"(a));
    return r;
}

// ---------------- prep: enc fp32 -> f16, same layout ----------------
__global__ __launch_bounds__(256) void prep_kernel(const float* __restrict__ enc,
                                                   f16* __restrict__ ench) {
    size_t i = ((size_t)blockIdx.x * 256 + threadIdx.x) * 8;
    float4 v0 = *(const float4*)(enc + i);
    float4 v1 = *(const float4*)(enc + i + 4);
    f16x8 o;
    o[0]=(f16)v0.x; o[1]=(f16)v0.y; o[2]=(f16)v0.z; o[3]=(f16)v0.w;
    o[4]=(f16)v1.x; o[5]=(f16)v1.y; o[6]=(f16)v1.z; o[7]=(f16)v1.w;
    *(f16x8*)(ench + i) = o;
}

// ---------------- fused attention: r5 core + in-register P + dual-acc QK + defer-max ----
// Structure = round-5 (best measured 64.2us): wave-decoupled, 32x32x16 MFMA, 4 waves x
// 32 t-cols, 1 barrier/iter, NAT dbuf 2x16KB, nsplit=4 over e, 512 blocks = 2/CU.
// Changes (all in-wave dataflow):
//  * P never touches LDS. QK C-layout: lane(t=l&31) holds P[e(r)=8(r>>2)+4hi+(r&3)].
//    PV B-frag (k = 8hi+j over each 16-e chunk) built by ONE shfl_xor(32) per chunk:
//    send = hi ? quad(r0..3) : quad(r4..7); j03 = hi ? recv : quad_lo; j47 = hi ? quad_hi
//    : recv. Verified against r5's LDS pf mapping (e = 16ks + 8hi + j) for both halves.
//  * Dual QK accumulators (even/odd ks) halve the 16-deep dependent MFMA chain.
//  * Defer-max THR=8 (T13): rescale only when mx > m_ + 8; m/l stored f32x2 (no snap).
// LDS = 32768 B (NAT only). Partials: z<2 -> ctxp f16 normalized; z=2 -> out[0:256) f32;
// z=3 -> out[256:512) f32 (parked; combine reads before overwriting) -- r8-proven layout.
__global__ __launch_bounds__(256, 2) void attn_kernel(
        const float* __restrict__ dec32,
        const f16*  __restrict__ enc_h,
        f16*   __restrict__ ctxp,
        f32x2* __restrict__ ml,
        float* __restrict__ out) {
    __shared__ __align__(16) char lds[32768];
    const int tid  = threadIdx.x;
    const int lane = tid & 63;
    const int wv   = tid >> 6;
    const int t5   = lane & 31;
    const int hi   = lane >> 5;

    const int fid = blockIdx.x + 16 * (blockIdx.y + 8 * blockIdx.z);
    const int b    = fid & 7;             // XCD pin
    const int rest = fid >> 3;
    const int xb   = rest & 15;
    const int z    = rest >> 4;           // 0..3
    const int t0   = xb * 128 + wv * 32;
    const int tile0 = z * 16;
    const int ITERS = 16;

    const char* encb = (const char*)(enc_h + (size_t)b * TE * DIM);

    // staging map (proven r2-r8)
    const int c0  = wv * 64 + lane;
    const int e_l = ((c0 >> 7) << 2) | ((c0 >> 1) & 3);
    const int d_l = (((c0 >> 3) & 15) << 4) | ((c0 & 1) << 3);
    const int stage_goff = e_l * (DIM * 2) + d_l * 2;
    char* stage_dst = lds + wv * 1024;

    const int qk_base = ((lane & 31) >> 2) * 2048 + (lane & 3) * 32 + hi * 16;
    const unsigned tr_base = (unsigned)(hi * 4096 + ((lane >> 4) & 1) * 128 + (lane & 15) * 8);
    const unsigned lds_base = lds_u32(lds);

    // Q fragments: B[k = ks*16 + hi*8 + j][n = t5]  (16 x f16x8 = 64 VGPR)
    f16x8 qf[16];
    {
        const float* qrow = dec32 + ((size_t)b * TD + t0 + t5) * DIM + hi * 8;
        #pragma unroll
        for (int ks = 0; ks < 16; ks++) {
            float4 u = *(const float4*)(qrow + ks * 16);
            float4 v = *(const float4*)(qrow + ks * 16 + 4);
            f16x8 o;
            o[0]=(f16)u.x; o[1]=(f16)u.y; o[2]=(f16)u.z; o[3]=(f16)u.w;
            o[4]=(f16)v.x; o[5]=(f16)v.y; o[6]=(f16)v.z; o[7]=(f16)v.w;
            qf[ks] = o;
        }
    }

    { // stage tile0 -> buf0
        const char* s = encb + (size_t)tile0 * 16384 + stage_goff;
        #pragma unroll
        for (int i = 0; i < 4; i++)
            __builtin_amdgcn_global_load_lds(AS1(s + i * 4096), AS3(stage_dst + i * 4096), 16, 0, 0);
    }

    float m_ = -INFINITY, l_ = 0.f;
    f32x16 ctx[8];
    #pragma unroll
    for (int dm = 0; dm < 8; dm++)
        #pragma unroll
        for (int r = 0; r < 16; r++) ctx[dm][r] = 0.f;

    __syncthreads();   // tile0 staged & drained

    for (int it = 0; it < ITERS; ++it) {
        const int nat = (it & 1) << 14;
        if (it + 1 < ITERS) {   // stage next tile; drained at end barrier (full window)
            const char* s = encb + (size_t)(tile0 + it + 1) * 16384 + stage_goff;
            char* dd = lds + (((it + 1) & 1) << 14) + wv * 1024;
            #pragma unroll
            for (int i = 0; i < 4; i++)
                __builtin_amdgcn_global_load_lds(AS1(s + i * 4096), AS3(dd + i * 4096), 16, 0, 0);
        }
        // ---- QK: St[e32][t32], 16 k-steps, dual accumulators (halved dep chain) ----
        f32x16 st0, st1;
        #pragma unroll
        for (int r = 0; r < 16; r++) { st0[r] = 0.f; st1[r] = 0.f; }
        const char* natp = lds + nat + qk_base;
        #pragma unroll
        for (int ks = 0; ks < 16; ks += 2) {
            f16x8 af0 = *(const f16x8*)(natp + ks * 128);
            f16x8 af1 = *(const f16x8*)(natp + ks * 128 + 128);
            st0 = MFMA32(af0, qf[ks],     st0);
            st1 = MFMA32(af1, qf[ks + 1], st1);
        }
        f32x16 st = st0 + st1;
        // ---- softmax (lane-local t-col), defer-max THR=8 ----
        float x0 = fmaxf(fmaxf(st[0], st[1]),  fmaxf(st[2], st[3]));
        float x1 = fmaxf(fmaxf(st[4], st[5]),  fmaxf(st[6], st[7]));
        float x2 = fmaxf(fmaxf(st[8], st[9]),  fmaxf(st[10], st[11]));
        float x3 = fmaxf(fmaxf(st[12], st[13]), fmaxf(st[14], st[15]));
        float mx = fmaxf(fmaxf(x0, x1), fmaxf(x2, x3));
        mx = fmaxf(mx, __shfl_xor(mx, 32, 64));
        bool bump = mx > m_ + 8.f;
        float ms = bump ? mx : m_;
        float al = bump ? __builtin_amdgcn_exp2f((m_ - ms) * LOG2E) : 1.f;
        m_ = ms;
        f16x4 pvg[4];
        float ssum = 0.f;
        #pragma unroll
        for (int g = 0; g < 4; g++) {           // local e = 8g + 4hi + r
            #pragma unroll
            for (int r = 0; r < 4; r++) {
                float p = __builtin_amdgcn_exp2f((st[4 * g + r] - ms) * LOG2E);
                pvg[g][r] = (f16)p;
                ssum += (float)pvg[g][r];
            }
        }
        ssum += __shfl_xor(ssum, 32, 64);
        l_ = l_ * al + ssum;
        if (__any(bump)) {
            #pragma unroll
            for (int dm = 0; dm < 8; dm++)
                #pragma unroll
                for (int r = 0; r < 16; r++) ctx[dm][r] *= al;
        }
        // ---- assemble PV B-frags in-register (1 shfl_xor(32) per 16-e chunk) ----
        f16x8 pfs[2];
        #pragma unroll
        for (int ks = 0; ks < 2; ks++) {
            f16x4 lo = pvg[2 * ks], hi4 = pvg[2 * ks + 1];
            f16x4 send = hi ? lo : hi4;
            u32x2 su = __builtin_bit_cast(u32x2, send);
            u32x2 ru;
            ru[0] = (unsigned)__shfl_xor((int)su[0], 32, 64);
            ru[1] = (unsigned)__shfl_xor((int)su[1], 32, 64);
            f16x4 recv = __builtin_bit_cast(f16x4, ru);
            f16x4 j03 = hi ? recv : lo;
            f16x4 j47 = hi ? hi4 : recv;
            pfs[ks] = SHUF8(j03, j47);
        }
        // ---- PV: ctx[d = dm*32 + row][t32]; A = enc^T tr-reads, B = pfs ----
        const unsigned trb = lds_base + (unsigned)nat + tr_base;
        #pragma unroll
        for (int ks = 0; ks < 2; ks++) {
            f16x8 pf = pfs[ks];
            const unsigned ab = trb + (unsigned)(ks * 8192);
            f16x4 a0 = tr_rd0(ab);        f16x4 a1 = tr_rd1(ab);
            f16x4 a2 = tr_rd0(ab + 256);  f16x4 a3 = tr_rd1(ab + 256);
            f16x4 a4 = tr_rd0(ab + 512);  f16x4 a5 = tr_rd1(ab + 512);
            f16x4 a6 = tr_rd0(ab + 768);  f16x4 a7 = tr_rd1(ab + 768);
            asm volatile("s_waitcnt lgkmcnt(0)" ::: "memory");
            __builtin_amdgcn_sched_barrier(0);
            ctx[0] = MFMA32(SHUF8(a0, a1), pf, ctx[0]);
            ctx[1] = MFMA32(SHUF8(a2, a3), pf, ctx[1]);
            ctx[2] = MFMA32(SHUF8(a4, a5), pf, ctx[2]);
            ctx[3] = MFMA32(SHUF8(a6, a7), pf, ctx[3]);
            f16x4 b0 = tr_rd0(ab + 1024); f16x4 b1 = tr_rd1(ab + 1024);
            f16x4 b2 = tr_rd0(ab + 1280); f16x4 b3 = tr_rd1(ab + 1280);
            f16x4 b4 = tr_rd0(ab + 1536); f16x4 b5 = tr_rd1(ab + 1536);
            f16x4 b6 = tr_rd0(ab + 1792); f16x4 b7 = tr_rd1(ab + 1792);
            asm volatile("s_waitcnt lgkmcnt(0)" ::: "memory");
            __builtin_amdgcn_sched_barrier(0);
            ctx[4] = MFMA32(SHUF8(b0, b1), pf, ctx[4]);
            ctx[5] = MFMA32(SHUF8(b2, b3), pf, ctx[5]);
            ctx[6] = MFMA32(SHUF8(b4, b5), pf, ctx[6]);
            ctx[7] = MFMA32(SHUF8(b6, b7), pf, ctx[7]);
        }
        __syncthreads();   // NAT dbuf protection + drains staging(it+1)
    }

    // ---- epilogue: normalized partials (r8-proven parking layout) ----
    const float inv = 1.0f / l_;
    const size_t row = (size_t)b * TD + t0 + t5;
    if (z < 2) {
        f16* cb = ctxp + ((size_t)z * NBTD + row) * DIM;
        #pragma unroll
        for (int dm = 0; dm < 8; dm++)
            #pragma unroll
            for (int g = 0; g < 4; g++) {
                f16x4 cv;
                #pragma unroll
                for (int r = 0; r < 4; r++) cv[r] = (f16)(ctx[dm][4 * g + r] * inv);
                *(f16x4*)(cb + dm * 32 + g * 8 + hi * 4) = cv;   // d = dm*32 + 8g + 4hi + r
            }
    } else {
        float* ob = out + row * 512 + (z == 3 ? 256 : 0);
        #pragma unroll
        for (int dm = 0; dm < 8; dm++)
            #pragma unroll
            for (int g = 0; g < 4; g++) {
                float4 cv;
                cv.x = ctx[dm][4 * g]     * inv;
                cv.y = ctx[dm][4 * g + 1] * inv;
                cv.z = ctx[dm][4 * g + 2] * inv;
                cv.w = ctx[dm][4 * g + 3] * inv;
                *(float4*)(ob + dm * 32 + g * 8 + hi * 4) = cv;
            }
    }
    if (hi == 0) {
        f32x2 v; v[0] = m_; v[1] = l_;
        ml[(size_t)z * NBTD + row] = v;
    }
}

// ---------------- combine: merge 4 normalized partials + decoder passthrough ----------
__global__ __launch_bounds__(256) void combine_kernel(const float* __restrict__ dec32,
        const f16* __restrict__ ctxp, const f32x2* __restrict__ ml,
        float* __restrict__ out) {
    int idx  = blockIdx.x * 256 + threadIdx.x;
    int trow = idx >> 5;              // b*TD + t
    int dg   = (idx & 31) * 8;
    float m0[4], l0[4], M = -INFINITY;
    #pragma unroll
    for (int s = 0; s < 4; s++) {
        f32x2 v = ml[(size_t)s * NBTD + trow];
        m0[s] = v[0];
        l0[s] = v[1];
        M = fmaxf(M, m0[s]);
    }
    float L = 0.f, w[4];
    #pragma unroll
    for (int s = 0; s < 4; s++) {
        w[s] = __builtin_amdgcn_exp2f((m0[s] - M) * LOG2E) * l0[s];
        L += w[s];
    }
    float invL = 1.0f / L;
    float acc[8];
    {   // splits 0,1: f16 partials in ctxp
        f16x8 v = *(const f16x8*)(ctxp + (size_t)trow * DIM + dg);
        float w0 = w[0] * invL;
        #pragma unroll
        for (int j = 0; j < 8; j++) acc[j] = w0 * (float)v[j];
        f16x8 u = *(const f16x8*)(ctxp + ((size_t)NBTD + trow) * DIM + dg);
        float w1 = w[1] * invL;
        #pragma unroll
        for (int j = 0; j < 8; j++) acc[j] += w1 * (float)u[j];
    }
    float* ob = out + (size_t)trow * 512;
    {   // split 2: parked in out[0:256)
        float4 p0 = *(const float4*)(ob + dg);
        float4 p1 = *(const float4*)(ob + dg + 4);
        float w2 = w[2] * invL;
        acc[0] += w2 * p0.x; acc[1] += w2 * p0.y; acc[2] += w2 * p0.z; acc[3] += w2 * p0.w;
        acc[4] += w2 * p1.x; acc[5] += w2 * p1.y; acc[6] += w2 * p1.z; acc[7] += w2 * p1.w;
    }
    {   // split 3: parked in out[256:512)
        float4 p0 = *(const float4*)(ob + 256 + dg);
        float4 p1 = *(const float4*)(ob + 256 + dg + 4);
        float w3 = w[3] * invL;
        acc[0] += w3 * p0.x; acc[1] += w3 * p0.y; acc[2] += w3 * p0.z; acc[3] += w3 * p0.w;
        acc[4] += w3 * p1.x; acc[5] += w3 * p1.y; acc[6] += w3 * p1.z; acc[7] += w3 * p1.w;
    }
    float4 d0 = *(const float4*)(dec32 + (size_t)trow * DIM + dg);
    float4 d1 = *(const float4*)(dec32 + (size_t)trow * DIM + dg + 4);
    *(float4*)(ob + dg)     = d0;
    *(float4*)(ob + dg + 4) = d1;
    float4 c0, c1;
    c0.x=acc[0]; c0.y=acc[1]; c0.z=acc[2]; c0.w=acc[3];
    c1.x=acc[4]; c1.y=acc[5]; c1.z=acc[6]; c1.w=acc[7];
    *(float4*)(ob + 256 + dg)     = c0;
    *(float4*)(ob + 256 + dg + 4) = c1;
}

extern "C" void kernel_launch(void* const* d_in, const int* in_sizes, int n_in,
                              void* d_out, int out_size, void* d_ws, size_t ws_size,
                              hipStream_t stream) {
    (void)in_sizes; (void)n_in;
    const float* enc = (const float*)d_in[0];
    const float* dec = (const float*)d_in[1];
    float* out = (float*)d_out;

    const size_t MLB  = (size_t)4 * NBTD * 8;         // 524,288 (f32x2 per split-row)
    const size_t HB   = (size_t)NB * TE * DIM * 2;    // 8,388,608 (ench)
    const size_t C2   = (size_t)2 * NBTD * DIM * 2;   // 16,777,216 (ctxp splits 0,1)
    const size_t NEED = MLB + HB + C2;                // 25,690,112 << proven 33.8 MB

    if (ws_size < NEED) {
        hipMemsetAsync(d_out, 0, (size_t)out_size * sizeof(float), stream);
        return;
    }
    f32x2* ml   = (f32x2*)d_ws;
    f16*   ench = (f16*)((char*)d_ws + MLB);
    f16*   ctxp = (f16*)((char*)d_ws + MLB + HB);

    prep_kernel<<<2048, 256, 0, stream>>>(enc, ench);
    attn_kernel<<<dim3(16, 8, 4), 256, 0, stream>>>(dec, ench, ctxp, ml, out);
    combine_kernel<<<2048, 256, 0, stream>>>(dec, ctxp, ml, out);
}

// Round 10
// 146.694 us; speedup vs baseline: 1.5676x; 1.0048x over previous
//
#include <hip/hip_runtime.h>

typedef _Float16 f16;
typedef _Float16 f16x4 __attribute__((ext_vector_type(4)));
typedef _Float16 f16x8 __attribute__((ext_vector_type(8)));
typedef float    f32x2 __attribute__((ext_vector_type(2)));
typedef float    f32x16 __attribute__((ext_vector_type(16)));
typedef unsigned u32x2 __attribute__((ext_vector_type(2)));

#define NB   8
#define TE   2048
#define TD   2048
#define DIM  256
#define NBTD (NB * TD)
#define LOG2E 1.44269504088896340736f

#define AS1(p) ((const __attribute__((address_space(1))) void*)(p))
#define AS3(p) ((__attribute__((address_space(3))) void*)(p))
#define MFMA32(a,b,c) __builtin_amdgcn_mfma_f32_32x32x16_f16((a),(b),(c),0,0,0)
#define SHUF8(x,y) __builtin_shufflevector((x),(y),0,1,2,3,4,5,6,7)

__device__ __forceinline__ unsigned lds_u32(void* p) {
    return (unsigned)(size_t)((__attribute__((address_space(3))) void*)p);
}
// ds_read_b64_tr_b16 (validated r4-r9): per-lane 8B payload at its own addr; in-group
// permutation delivers out[l][j] = block[row j][col l&15] for a 4x16 row-major 128B
// block when per-lane addr = block_base + (l&15)*8.
__device__ __forceinline__ f16x4 tr_rd0(unsigned a) {
    f16x4 r;
    asm volatile("ds_read_b64_tr_b16 %0, %1" : "=v"(r) : "v"(a));
    return r;
}
__device__ __forceinline__ f16x4 tr_rd1(unsigned a) {   // +2048 = next e4 subtile row
    f16x4 r;
    asm volatile("ds_read_b64_tr_b16 %0, %1 offset:2048" : "=v"(r) : "v"(a));
    return r;
}

// ---------------- prep: enc fp32 -> f16, same layout ----------------
__global__ __launch_bounds__(256) void prep_kernel(const float* __restrict__ enc,
                                                   f16* __restrict__ ench) {
    size_t i = ((size_t)blockIdx.x * 256 + threadIdx.x) * 8;
    float4 v0 = *(const float4*)(enc + i);
    float4 v1 = *(const float4*)(enc + i + 4);
    f16x8 o;
    o[0]=(f16)v0.x; o[1]=(f16)v0.y; o[2]=(f16)v0.z; o[3]=(f16)v0.w;
    o[4]=(f16)v1.x; o[5]=(f16)v1.y; o[6]=(f16)v1.z; o[7]=(f16)v1.w;
    *(f16x8*)(ench + i) = o;
}

// ---------------- fused attention: r9 core + e64 windows (1 barrier / 2 sub-iters) + setprio ----
// Core body (QK dual-acc 32x32x16, in-register P via 1 shfl_xor(32)/chunk, defer-max
// THR=8, tr-read PV) byte-identical to round-9. Changes:
//  * NAT buffers 2 x 32 KB: each window holds TWO e32 sub-tiles (contiguous in ench;
//    staging chunk map extends linearly across the 16 KB sub-tile boundary). Two
//    sub-iterations per __syncthreads -> barriers/block 16 -> 8, and each 32 KB staging
//    batch drains a full window (~2x longer cover) later.
//  * T5: s_setprio(1) around the QK MFMA loop and each PV 4-MFMA cluster.
// LDS 65,536 B -> 2 blocks/CU (unchanged occupancy). Partials layout = r8/r9 proven:
// z<2 -> ctxp f16 normalized; z=2 -> out[0:256) f32; z=3 -> out[256:512) f32 (parked).
__global__ __launch_bounds__(256, 2) void attn_kernel(
        const float* __restrict__ dec32,
        const f16*  __restrict__ enc_h,
        f16*   __restrict__ ctxp,
        f32x2* __restrict__ ml,
        float* __restrict__ out) {
    __shared__ __align__(16) char lds[65536];
    const int tid  = threadIdx.x;
    const int lane = tid & 63;
    const int wv   = tid >> 6;
    const int t5   = lane & 31;
    const int hi   = lane >> 5;

    const int fid = blockIdx.x + 16 * (blockIdx.y + 8 * blockIdx.z);
    const int b    = fid & 7;             // XCD pin
    const int rest = fid >> 3;
    const int xb   = rest & 15;
    const int z    = rest >> 4;           // 0..3
    const int t0   = xb * 128 + wv * 32;
    const int tile0 = z * 16;             // 16 e32-tiles per split = 8 windows
    const int WND = 8;

    const char* encb = (const char*)(enc_h + (size_t)b * TE * DIM);

    // staging map (proven r2-r9); extends linearly over 2 sub-tiles (i = 0..7)
    const int c0  = wv * 64 + lane;
    const int e_l = ((c0 >> 7) << 2) | ((c0 >> 1) & 3);
    const int d_l = (((c0 >> 3) & 15) << 4) | ((c0 & 1) << 3);
    const int stage_goff = e_l * (DIM * 2) + d_l * 2;

    const int qk_base = ((lane & 31) >> 2) * 2048 + (lane & 3) * 32 + hi * 16;
    const unsigned tr_base = (unsigned)(hi * 4096 + ((lane >> 4) & 1) * 128 + (lane & 15) * 8);
    const unsigned lds_base = lds_u32(lds);

    // Q fragments: B[k = ks*16 + hi*8 + j][n = t5]  (16 x f16x8 = 64 VGPR)
    f16x8 qf[16];
    {
        const float* qrow = dec32 + ((size_t)b * TD + t0 + t5) * DIM + hi * 8;
        #pragma unroll
        for (int ks = 0; ks < 16; ks++) {
            float4 u = *(const float4*)(qrow + ks * 16);
            float4 v = *(const float4*)(qrow + ks * 16 + 4);
            f16x8 o;
            o[0]=(f16)u.x; o[1]=(f16)u.y; o[2]=(f16)u.z; o[3]=(f16)u.w;
            o[4]=(f16)v.x; o[5]=(f16)v.y; o[6]=(f16)v.z; o[7]=(f16)v.w;
            qf[ks] = o;
        }
    }

    { // stage window 0 (tiles tile0, tile0+1 = 32 KB) -> buf0
        const char* s = encb + (size_t)tile0 * 16384 + stage_goff;
        #pragma unroll
        for (int i = 0; i < 8; i++)
            __builtin_amdgcn_global_load_lds(AS1(s + i * 4096),
                                             AS3(lds + wv * 1024 + i * 4096), 16, 0, 0);
    }

    float m_ = -INFINITY, l_ = 0.f;
    f32x16 ctx[8];
    #pragma unroll
    for (int dm = 0; dm < 8; dm++)
        #pragma unroll
        for (int r = 0; r < 16; r++) ctx[dm][r] = 0.f;

    __syncthreads();   // window 0 staged & drained

    for (int wnd = 0; wnd < WND; ++wnd) {
        if (wnd + 1 < WND) {   // stage next window (32 KB) -> other buffer
            const char* s = encb + (size_t)(tile0 + 2 * (wnd + 1)) * 16384 + stage_goff;
            char* dd = lds + (((wnd + 1) & 1) << 15) + wv * 1024;
            #pragma unroll
            for (int i = 0; i < 8; i++)
                __builtin_amdgcn_global_load_lds(AS1(s + i * 4096), AS3(dd + i * 4096), 16, 0, 0);
        }
        #pragma unroll
        for (int sub = 0; sub < 2; ++sub) {
            const int nat = ((wnd & 1) << 15) + (sub << 14);
            // ---- QK: St[e32][t32], 16 k-steps, dual accumulators ----
            f32x16 st0, st1;
            #pragma unroll
            for (int r = 0; r < 16; r++) { st0[r] = 0.f; st1[r] = 0.f; }
            const char* natp = lds + nat + qk_base;
            __builtin_amdgcn_s_setprio(1);
            #pragma unroll
            for (int ks = 0; ks < 16; ks += 2) {
                f16x8 af0 = *(const f16x8*)(natp + ks * 128);
                f16x8 af1 = *(const f16x8*)(natp + ks * 128 + 128);
                st0 = MFMA32(af0, qf[ks],     st0);
                st1 = MFMA32(af1, qf[ks + 1], st1);
            }
            __builtin_amdgcn_s_setprio(0);
            f32x16 st = st0 + st1;
            // ---- softmax (lane-local t-col), defer-max THR=8 ----
            float x0 = fmaxf(fmaxf(st[0], st[1]),  fmaxf(st[2], st[3]));
            float x1 = fmaxf(fmaxf(st[4], st[5]),  fmaxf(st[6], st[7]));
            float x2 = fmaxf(fmaxf(st[8], st[9]),  fmaxf(st[10], st[11]));
            float x3 = fmaxf(fmaxf(st[12], st[13]), fmaxf(st[14], st[15]));
            float mx = fmaxf(fmaxf(x0, x1), fmaxf(x2, x3));
            mx = fmaxf(mx, __shfl_xor(mx, 32, 64));
            bool bump = mx > m_ + 8.f;
            float ms = bump ? mx : m_;
            float al = bump ? __builtin_amdgcn_exp2f((m_ - ms) * LOG2E) : 1.f;
            m_ = ms;
            f16x4 pvg[4];
            float ssum = 0.f;
            #pragma unroll
            for (int g = 0; g < 4; g++) {           // local e = 8g + 4hi + r
                #pragma unroll
                for (int r = 0; r < 4; r++) {
                    float p = __builtin_amdgcn_exp2f((st[4 * g + r] - ms) * LOG2E);
                    pvg[g][r] = (f16)p;
                    ssum += (float)pvg[g][r];
                }
            }
            ssum += __shfl_xor(ssum, 32, 64);
            l_ = l_ * al + ssum;
            if (__any(bump)) {
                #pragma unroll
                for (int dm = 0; dm < 8; dm++)
                    #pragma unroll
                    for (int r = 0; r < 16; r++) ctx[dm][r] *= al;
            }
            // ---- assemble PV B-frags in-register (1 shfl_xor(32) per 16-e chunk) ----
            f16x8 pfs[2];
            #pragma unroll
            for (int ks = 0; ks < 2; ks++) {
                f16x4 lo = pvg[2 * ks], hi4 = pvg[2 * ks + 1];
                f16x4 send = hi ? lo : hi4;
                u32x2 su = __builtin_bit_cast(u32x2, send);
                u32x2 ru;
                ru[0] = (unsigned)__shfl_xor((int)su[0], 32, 64);
                ru[1] = (unsigned)__shfl_xor((int)su[1], 32, 64);
                f16x4 recv = __builtin_bit_cast(f16x4, ru);
                f16x4 j03 = hi ? recv : lo;
                f16x4 j47 = hi ? hi4 : recv;
                pfs[ks] = SHUF8(j03, j47);
            }
            // ---- PV: ctx[d = dm*32 + row][t32]; A = enc^T tr-reads, B = pfs ----
            const unsigned trb = lds_base + (unsigned)nat + tr_base;
            #pragma unroll
            for (int ks = 0; ks < 2; ks++) {
                f16x8 pf = pfs[ks];
                const unsigned ab = trb + (unsigned)(ks * 8192);
                f16x4 a0 = tr_rd0(ab);        f16x4 a1 = tr_rd1(ab);
                f16x4 a2 = tr_rd0(ab + 256);  f16x4 a3 = tr_rd1(ab + 256);
                f16x4 a4 = tr_rd0(ab + 512);  f16x4 a5 = tr_rd1(ab + 512);
                f16x4 a6 = tr_rd0(ab + 768);  f16x4 a7 = tr_rd1(ab + 768);
                asm volatile("s_waitcnt lgkmcnt(0)" ::: "memory");
                __builtin_amdgcn_sched_barrier(0);
                __builtin_amdgcn_s_setprio(1);
                ctx[0] = MFMA32(SHUF8(a0, a1), pf, ctx[0]);
                ctx[1] = MFMA32(SHUF8(a2, a3), pf, ctx[1]);
                ctx[2] = MFMA32(SHUF8(a4, a5), pf, ctx[2]);
                ctx[3] = MFMA32(SHUF8(a6, a7), pf, ctx[3]);
                __builtin_amdgcn_s_setprio(0);
                f16x4 b0 = tr_rd0(ab + 1024); f16x4 b1 = tr_rd1(ab + 1024);
                f16x4 b2 = tr_rd0(ab + 1280); f16x4 b3 = tr_rd1(ab + 1280);
                f16x4 b4 = tr_rd0(ab + 1536); f16x4 b5 = tr_rd1(ab + 1536);
                f16x4 b6 = tr_rd0(ab + 1792); f16x4 b7 = tr_rd1(ab + 1792);
                asm volatile("s_waitcnt lgkmcnt(0)" ::: "memory");
                __builtin_amdgcn_sched_barrier(0);
                __builtin_amdgcn_s_setprio(1);
                ctx[4] = MFMA32(SHUF8(b0, b1), pf, ctx[4]);
                ctx[5] = MFMA32(SHUF8(b2, b3), pf, ctx[5]);
                ctx[6] = MFMA32(SHUF8(b4, b5), pf, ctx[6]);
                ctx[7] = MFMA32(SHUF8(b6, b7), pf, ctx[7]);
                __builtin_amdgcn_s_setprio(0);
            }
        }
        __syncthreads();   // window barrier: NAT dbuf protection + drains staging
    }

    // ---- epilogue: normalized partials (r8/r9-proven parking layout) ----
    const float inv = 1.0f / l_;
    const size_t row = (size_t)b * TD + t0 + t5;
    if (z < 2) {
        f16* cb = ctxp + ((size_t)z * NBTD + row) * DIM;
        #pragma unroll
        for (int dm = 0; dm < 8; dm++)
            #pragma unroll
            for (int g = 0; g < 4; g++) {
                f16x4 cv;
                #pragma unroll
                for (int r = 0; r < 4; r++) cv[r] = (f16)(ctx[dm][4 * g + r] * inv);
                *(f16x4*)(cb + dm * 32 + g * 8 + hi * 4) = cv;   // d = dm*32 + 8g + 4hi + r
            }
    } else {
        float* ob = out + row * 512 + (z == 3 ? 256 : 0);
        #pragma unroll
        for (int dm = 0; dm < 8; dm++)
            #pragma unroll
            for (int g = 0; g < 4; g++) {
                float4 cv;
                cv.x = ctx[dm][4 * g]     * inv;
                cv.y = ctx[dm][4 * g + 1] * inv;
                cv.z = ctx[dm][4 * g + 2] * inv;
                cv.w = ctx[dm][4 * g + 3] * inv;
                *(float4*)(ob + dm * 32 + g * 8 + hi * 4) = cv;
            }
    }
    if (hi == 0) {
        f32x2 v; v[0] = m_; v[1] = l_;
        ml[(size_t)z * NBTD + row] = v;
    }
}

// ---------------- combine: merge 4 normalized partials + decoder passthrough ----------
__global__ __launch_bounds__(256) void combine_kernel(const float* __restrict__ dec32,
        const f16* __restrict__ ctxp, const f32x2* __restrict__ ml,
        float* __restrict__ out) {
    int idx  = blockIdx.x * 256 + threadIdx.x;
    int trow = idx >> 5;              // b*TD + t
    int dg   = (idx & 31) * 8;
    float m0[4], l0[4], M = -INFINITY;
    #pragma unroll
    for (int s = 0; s < 4; s++) {
        f32x2 v = ml[(size_t)s * NBTD + trow];
        m0[s] = v[0];
        l0[s] = v[1];
        M = fmaxf(M, m0[s]);
    }
    float L = 0.f, w[4];
    #pragma unroll
    for (int s = 0; s < 4; s++) {
        w[s] = __builtin_amdgcn_exp2f((m0[s] - M) * LOG2E) * l0[s];
        L += w[s];
    }
    float invL = 1.0f / L;
    float acc[8];
    {   // splits 0,1: f16 partials in ctxp
        f16x8 v = *(const f16x8*)(ctxp + (size_t)trow * DIM + dg);
        float w0 = w[0] * invL;
        #pragma unroll
        for (int j = 0; j < 8; j++) acc[j] = w0 * (float)v[j];
        f16x8 u = *(const f16x8*)(ctxp + ((size_t)NBTD + trow) * DIM + dg);
        float w1 = w[1] * invL;
        #pragma unroll
        for (int j = 0; j < 8; j++) acc[j] += w1 * (float)u[j];
    }
    float* ob = out + (size_t)trow * 512;
    {   // split 2: parked in out[0:256)
        float4 p0 = *(const float4*)(ob + dg);
        float4 p1 = *(const float4*)(ob + dg + 4);
        float w2 = w[2] * invL;
        acc[0] += w2 * p0.x; acc[1] += w2 * p0.y; acc[2] += w2 * p0.z; acc[3] += w2 * p0.w;
        acc[4] += w2 * p1.x; acc[5] += w2 * p1.y; acc[6] += w2 * p1.z; acc[7] += w2 * p1.w;
    }
    {   // split 3: parked in out[256:512)
        float4 p0 = *(const float4*)(ob + 256 + dg);
        float4 p1 = *(const float4*)(ob + 256 + dg + 4);
        float w3 = w[3] * invL;
        acc[0] += w3 * p0.x; acc[1] += w3 * p0.y; acc[2] += w3 * p0.z; acc[3] += w3 * p0.w;
        acc[4] += w3 * p1.x; acc[5] += w3 * p1.y; acc[6] += w3 * p1.z; acc[7] += w3 * p1.w;
    }
    float4 d0 = *(const float4*)(dec32 + (size_t)trow * DIM + dg);
    float4 d1 = *(const float4*)(dec32 + (size_t)trow * DIM + dg + 4);
    *(float4*)(ob + dg)     = d0;
    *(float4*)(ob + dg + 4) = d1;
    float4 c0, c1;
    c0.x=acc[0]; c0.y=acc[1]; c0.z=acc[2]; c0.w=acc[3];
    c1.x=acc[4]; c1.y=acc[5]; c1.z=acc[6]; c1.w=acc[7];
    *(float4*)(ob + 256 + dg)     = c0;
    *(float4*)(ob + 256 + dg + 4) = c1;
}

extern "C" void kernel_launch(void* const* d_in, const int* in_sizes, int n_in,
                              void* d_out, int out_size, void* d_ws, size_t ws_size,
                              hipStream_t stream) {
    (void)in_sizes; (void)n_in;
    const float* enc = (const float*)d_in[0];
    const float* dec = (const float*)d_in[1];
    float* out = (float*)d_out;

    const size_t MLB  = (size_t)4 * NBTD * 8;         // 524,288 (f32x2 per split-row)
    const size_t HB   = (size_t)NB * TE * DIM * 2;    // 8,388,608 (ench)
    const size_t C2   = (size_t)2 * NBTD * DIM * 2;   // 16,777,216 (ctxp splits 0,1)
    const size_t NEED = MLB + HB + C2;                // 25,690,112 << proven 33.8 MB

    if (ws_size < NEED) {
        hipMemsetAsync(d_out, 0, (size_t)out_size * sizeof(float), stream);
        return;
    }
    f32x2* ml   = (f32x2*)d_ws;
    f16*   ench = (f16*)((char*)d_ws + MLB);
    f16*   ctxp = (f16*)((char*)d_ws + MLB + HB);

    prep_kernel<<<2048, 256, 0, stream>>>(enc, ench);
    attn_kernel<<<dim3(16, 8, 4), 256, 0, stream>>>(dec, ench, ctxp, ml, out);
    combine_kernel<<<2048, 256, 0, stream>>>(dec, ctxp, ml, out);
}

// Round 11
// 145.169 us; speedup vs baseline: 1.5841x; 1.0105x over previous
//
#include <hip/hip_runtime.h>

typedef _Float16 f16;
typedef _Float16 f16x4 __attribute__((ext_vector_type(4)));
typedef _Float16 f16x8 __attribute__((ext_vector_type(8)));
typedef float    f32x2 __attribute__((ext_vector_type(2)));
typedef float    f32x16 __attribute__((ext_vector_type(16)));
typedef unsigned u32x2 __attribute__((ext_vector_type(2)));

#define NB   8
#define TE   2048
#define TD   2048
#define DIM  256
#define NBTD (NB * TD)
#define LOG2E 1.44269504088896340736f

#define AS1(p) ((const __attribute__((address_space(1))) void*)(p))
#define AS3(p) ((__attribute__((address_space(3))) void*)(p))
#define MFMA32(a,b,c) __builtin_amdgcn_mfma_f32_32x32x16_f16((a),(b),(c),0,0,0)
#define SHUF8(x,y) __builtin_shufflevector((x),(y),0,1,2,3,4,5,6,7)
#define SB __builtin_amdgcn_sched_barrier(0)
#define LGKM(n) asm volatile("s_waitcnt lgkmcnt(" #n ")" ::: "memory")

__device__ __forceinline__ unsigned lds_u32(void* p) {
    return (unsigned)(size_t)((__attribute__((address_space(3))) void*)p);
}
// ds_read_b64_tr_b16 (validated r4-r10): per-lane 8B payload at its own addr; in-group
// permutation delivers out[l][j] = block[row j][col l&15] for a 4x16 row-major 128B
// block when per-lane addr = block_base + (l&15)*8.
__device__ __forceinline__ f16x4 tr_rd0(unsigned a) {
    f16x4 r;
    asm volatile("ds_read_b64_tr_b16 %0, %1" : "=v"(r) : "v"(a));
    return r;
}
__device__ __forceinline__ f16x4 tr_rd1(unsigned a) {   // +2048 = next e4 subtile row
    f16x4 r;
    asm volatile("ds_read_b64_tr_b16 %0, %1 offset:2048" : "=v"(r) : "v"(a));
    return r;
}
// PV pipeline helpers: unit = 2 tr-reads (base OFF, OFF+2048) -> 1 MFMA into ctx[dm]
#define TRI(s, OFF) s##a = tr_rd0(trv + (OFF)); s##b = tr_rd1(trv + (OFF))
#define PVU(s, dmv, pfv) ctx[dmv] = MFMA32(SHUF8(s##a, s##b), (pfv), ctx[dmv])

// ---------------- prep: enc fp32 -> f16, same layout ----------------
__global__ __launch_bounds__(256) void prep_kernel(const float* __restrict__ enc,
                                                   f16* __restrict__ ench) {
    size_t i = ((size_t)blockIdx.x * 256 + threadIdx.x) * 8;
    float4 v0 = *(const float4*)(enc + i);
    float4 v1 = *(const float4*)(enc + i + 4);
    f16x8 o;
    o[0]=(f16)v0.x; o[1]=(f16)v0.y; o[2]=(f16)v0.z; o[3]=(f16)v0.w;
    o[4]=(f16)v1.x; o[5]=(f16)v1.y; o[6]=(f16)v1.z; o[7]=(f16)v1.w;
    *(f16x8*)(ench + i) = o;
}

// ---------------- fused attention: r10 + counted-lgkmcnt PV pipeline ----------------
// Base = round-10 (e64 windows, 1 barrier / 2 sub-iters, QK dual-acc + setprio,
// in-register P, defer-max THR=8). ONLY change: PV restructured into 16 units
// (2 tr-reads -> 1 MFMA), software-pipelined 4-deep with counted lgkmcnt(6) waits
// (never 0 mid-loop; tail 6/4/2/0) + sched_barrier after each wait (rule #18).
// Counting exactness: all softmax/pfs shuffle results are consumed ABOVE the SB that
// precedes the pre-issue, so the only outstanding LGKM ops in the PV region are the
// 8 asm tr-reads in flight. PV setprio toggles removed (r10: neutral).
__global__ __launch_bounds__(256, 2) void attn_kernel(
        const float* __restrict__ dec32,
        const f16*  __restrict__ enc_h,
        f16*   __restrict__ ctxp,
        f32x2* __restrict__ ml,
        float* __restrict__ out) {
    __shared__ __align__(16) char lds[65536];
    const int tid  = threadIdx.x;
    const int lane = tid & 63;
    const int wv   = tid >> 6;
    const int t5   = lane & 31;
    const int hi   = lane >> 5;

    const int fid = blockIdx.x + 16 * (blockIdx.y + 8 * blockIdx.z);
    const int b    = fid & 7;             // XCD pin
    const int rest = fid >> 3;
    const int xb   = rest & 15;
    const int z    = rest >> 4;           // 0..3
    const int t0   = xb * 128 + wv * 32;
    const int tile0 = z * 16;             // 16 e32-tiles per split = 8 windows
    const int WND = 8;

    const char* encb = (const char*)(enc_h + (size_t)b * TE * DIM);

    // staging map (proven r2-r10); extends linearly over 2 sub-tiles (i = 0..7)
    const int c0  = wv * 64 + lane;
    const int e_l = ((c0 >> 7) << 2) | ((c0 >> 1) & 3);
    const int d_l = (((c0 >> 3) & 15) << 4) | ((c0 & 1) << 3);
    const int stage_goff = e_l * (DIM * 2) + d_l * 2;

    const int qk_base = ((lane & 31) >> 2) * 2048 + (lane & 3) * 32 + hi * 16;
    const unsigned tr_base = (unsigned)(hi * 4096 + ((lane >> 4) & 1) * 128 + (lane & 15) * 8);
    const unsigned lds_base = lds_u32(lds);

    // Q fragments: B[k = ks*16 + hi*8 + j][n = t5]  (16 x f16x8 = 64 VGPR)
    f16x8 qf[16];
    {
        const float* qrow = dec32 + ((size_t)b * TD + t0 + t5) * DIM + hi * 8;
        #pragma unroll
        for (int ks = 0; ks < 16; ks++) {
            float4 u = *(const float4*)(qrow + ks * 16);
            float4 v = *(const float4*)(qrow + ks * 16 + 4);
            f16x8 o;
            o[0]=(f16)u.x; o[1]=(f16)u.y; o[2]=(f16)u.z; o[3]=(f16)u.w;
            o[4]=(f16)v.x; o[5]=(f16)v.y; o[6]=(f16)v.z; o[7]=(f16)v.w;
            qf[ks] = o;
        }
    }

    { // stage window 0 (tiles tile0, tile0+1 = 32 KB) -> buf0
        const char* s = encb + (size_t)tile0 * 16384 + stage_goff;
        #pragma unroll
        for (int i = 0; i < 8; i++)
            __builtin_amdgcn_global_load_lds(AS1(s + i * 4096),
                                             AS3(lds + wv * 1024 + i * 4096), 16, 0, 0);
    }

    float m_ = -INFINITY, l_ = 0.f;
    f32x16 ctx[8];
    #pragma unroll
    for (int dm = 0; dm < 8; dm++)
        #pragma unroll
        for (int r = 0; r < 16; r++) ctx[dm][r] = 0.f;

    __syncthreads();   // window 0 staged & drained

    for (int wnd = 0; wnd < WND; ++wnd) {
        if (wnd + 1 < WND) {   // stage next window (32 KB) -> other buffer
            const char* s = encb + (size_t)(tile0 + 2 * (wnd + 1)) * 16384 + stage_goff;
            char* dd = lds + (((wnd + 1) & 1) << 15) + wv * 1024;
            #pragma unroll
            for (int i = 0; i < 8; i++)
                __builtin_amdgcn_global_load_lds(AS1(s + i * 4096), AS3(dd + i * 4096), 16, 0, 0);
        }
        #pragma unroll
        for (int sub = 0; sub < 2; ++sub) {
            const int nat = ((wnd & 1) << 15) + (sub << 14);
            // ---- QK: St[e32][t32], 16 k-steps, dual accumulators ----
            f32x16 st0, st1;
            #pragma unroll
            for (int r = 0; r < 16; r++) { st0[r] = 0.f; st1[r] = 0.f; }
            const char* natp = lds + nat + qk_base;
            __builtin_amdgcn_s_setprio(1);
            #pragma unroll
            for (int ks = 0; ks < 16; ks += 2) {
                f16x8 af0 = *(const f16x8*)(natp + ks * 128);
                f16x8 af1 = *(const f16x8*)(natp + ks * 128 + 128);
                st0 = MFMA32(af0, qf[ks],     st0);
                st1 = MFMA32(af1, qf[ks + 1], st1);
            }
            __builtin_amdgcn_s_setprio(0);
            f32x16 st = st0 + st1;
            // ---- softmax (lane-local t-col), defer-max THR=8 ----
            float x0 = fmaxf(fmaxf(st[0], st[1]),  fmaxf(st[2], st[3]));
            float x1 = fmaxf(fmaxf(st[4], st[5]),  fmaxf(st[6], st[7]));
            float x2 = fmaxf(fmaxf(st[8], st[9]),  fmaxf(st[10], st[11]));
            float x3 = fmaxf(fmaxf(st[12], st[13]), fmaxf(st[14], st[15]));
            float mx = fmaxf(fmaxf(x0, x1), fmaxf(x2, x3));
            mx = fmaxf(mx, __shfl_xor(mx, 32, 64));
            bool bump = mx > m_ + 8.f;
            float ms = bump ? mx : m_;
            float al = bump ? __builtin_amdgcn_exp2f((m_ - ms) * LOG2E) : 1.f;
            m_ = ms;
            f16x4 pvg[4];
            float ssum = 0.f;
            #pragma unroll
            for (int g = 0; g < 4; g++) {           // local e = 8g + 4hi + r
                #pragma unroll
                for (int r = 0; r < 4; r++) {
                    float p = __builtin_amdgcn_exp2f((st[4 * g + r] - ms) * LOG2E);
                    pvg[g][r] = (f16)p;
                    ssum += (float)pvg[g][r];
                }
            }
            ssum += __shfl_xor(ssum, 32, 64);
            l_ = l_ * al + ssum;
            if (__any(bump)) {
                #pragma unroll
                for (int dm = 0; dm < 8; dm++)
                    #pragma unroll
                    for (int r = 0; r < 16; r++) ctx[dm][r] *= al;
            }
            // ---- assemble PV B-frags in-register (1 shfl_xor(32) per 16-e chunk);
            //      ALL shuffle results consumed here, above the SB ----
            f16x8 pfs[2];
            #pragma unroll
            for (int ks = 0; ks < 2; ks++) {
                f16x4 lo = pvg[2 * ks], hi4 = pvg[2 * ks + 1];
                f16x4 send = hi ? lo : hi4;
                u32x2 su = __builtin_bit_cast(u32x2, send);
                u32x2 ru;
                ru[0] = (unsigned)__shfl_xor((int)su[0], 32, 64);
                ru[1] = (unsigned)__shfl_xor((int)su[1], 32, 64);
                f16x4 recv = __builtin_bit_cast(f16x4, ru);
                f16x4 j03 = hi ? recv : lo;
                f16x4 j47 = hi ? hi4 : recv;
                pfs[ks] = SHUF8(j03, j47);
            }
            // ---- PV: 16 units (2 tr-reads -> 1 MFMA), 4-deep counted pipeline ----
            // unit(ks,dm) reads trv + ks*8192 + dm*256 (+2048 pair); consume order =
            // issue order; lgkmcnt(6) = 3 units (6 reads) still in flight.
            const unsigned trv = lds_base + (unsigned)nat + tr_base;
            f16x4 s0a, s0b, s1a, s1b, s2a, s2b, s3a, s3b;
            SB;                                   // nothing crosses into the counted region
            TRI(s0, 0);    TRI(s1, 256);  TRI(s2, 512);  TRI(s3, 768);
            LGKM(6); SB; PVU(s0, 0, pfs[0]); TRI(s0, 1024);
            LGKM(6); SB; PVU(s1, 1, pfs[0]); TRI(s1, 1280);
            LGKM(6); SB; PVU(s2, 2, pfs[0]); TRI(s2, 1536);
            LGKM(6); SB; PVU(s3, 3, pfs[0]); TRI(s3, 1792);
            LGKM(6); SB; PVU(s0, 4, pfs[0]); TRI(s0, 8192);
            LGKM(6); SB; PVU(s1, 5, pfs[0]); TRI(s1, 8448);
            LGKM(6); SB; PVU(s2, 6, pfs[0]); TRI(s2, 8704);
            LGKM(6); SB; PVU(s3, 7, pfs[0]); TRI(s3, 8960);
            LGKM(6); SB; PVU(s0, 0, pfs[1]); TRI(s0, 9216);
            LGKM(6); SB; PVU(s1, 1, pfs[1]); TRI(s1, 9472);
            LGKM(6); SB; PVU(s2, 2, pfs[1]); TRI(s2, 9728);
            LGKM(6); SB; PVU(s3, 3, pfs[1]); TRI(s3, 9984);
            LGKM(6); SB; PVU(s0, 4, pfs[1]);
            LGKM(4); SB; PVU(s1, 5, pfs[1]);
            LGKM(2); SB; PVU(s2, 6, pfs[1]);
            LGKM(0); SB; PVU(s3, 7, pfs[1]);
        }
        __syncthreads();   // window barrier: NAT dbuf protection + drains staging
    }

    // ---- epilogue: normalized partials (r8-r10 proven parking layout) ----
    const float inv = 1.0f / l_;
    const size_t row = (size_t)b * TD + t0 + t5;
    if (z < 2) {
        f16* cb = ctxp + ((size_t)z * NBTD + row) * DIM;
        #pragma unroll
        for (int dm = 0; dm < 8; dm++)
            #pragma unroll
            for (int g = 0; g < 4; g++) {
                f16x4 cv;
                #pragma unroll
                for (int r = 0; r < 4; r++) cv[r] = (f16)(ctx[dm][4 * g + r] * inv);
                *(f16x4*)(cb + dm * 32 + g * 8 + hi * 4) = cv;   // d = dm*32 + 8g + 4hi + r
            }
    } else {
        float* ob = out + row * 512 + (z == 3 ? 256 : 0);
        #pragma unroll
        for (int dm = 0; dm < 8; dm++)
            #pragma unroll
            for (int g = 0; g < 4; g++) {
                float4 cv;
                cv.x = ctx[dm][4 * g]     * inv;
                cv.y = ctx[dm][4 * g + 1] * inv;
                cv.z = ctx[dm][4 * g + 2] * inv;
                cv.w = ctx[dm][4 * g + 3] * inv;
                *(float4*)(ob + dm * 32 + g * 8 + hi * 4) = cv;
            }
    }
    if (hi == 0) {
        f32x2 v; v[0] = m_; v[1] = l_;
        ml[(size_t)z * NBTD + row] = v;
    }
}

// ---------------- combine: merge 4 normalized partials + decoder passthrough ----------
__global__ __launch_bounds__(256) void combine_kernel(const float* __restrict__ dec32,
        const f16* __restrict__ ctxp, const f32x2* __restrict__ ml,
        float* __restrict__ out) {
    int idx  = blockIdx.x * 256 + threadIdx.x;
    int trow = idx >> 5;              // b*TD + t
    int dg   = (idx & 31) * 8;
    float m0[4], l0[4], M = -INFINITY;
    #pragma unroll
    for (int s = 0; s < 4; s++) {
        f32x2 v = ml[(size_t)s * NBTD + trow];
        m0[s] = v[0];
        l0[s] = v[1];
        M = fmaxf(M, m0[s]);
    }
    float L = 0.f, w[4];
    #pragma unroll
    for (int s = 0; s < 4; s++) {
        w[s] = __builtin_amdgcn_exp2f((m0[s] - M) * LOG2E) * l0[s];
        L += w[s];
    }
    float invL = 1.0f / L;
    float acc[8];
    {   // splits 0,1: f16 partials in ctxp
        f16x8 v = *(const f16x8*)(ctxp + (size_t)trow * DIM + dg);
        float w0 = w[0] * invL;
        #pragma unroll
        for (int j = 0; j < 8; j++) acc[j] = w0 * (float)v[j];
        f16x8 u = *(const f16x8*)(ctxp + ((size_t)NBTD + trow) * DIM + dg);
        float w1 = w[1] * invL;
        #pragma unroll
        for (int j = 0; j < 8; j++) acc[j] += w1 * (float)u[j];
    }
    float* ob = out + (size_t)trow * 512;
    {   // split 2: parked in out[0:256)
        float4 p0 = *(const float4*)(ob + dg);
        float4 p1 = *(const float4*)(ob + dg + 4);
        float w2 = w[2] * invL;
        acc[0] += w2 * p0.x; acc[1] += w2 * p0.y; acc[2] += w2 * p0.z; acc[3] += w2 * p0.w;
        acc[4] += w2 * p1.x; acc[5] += w2 * p1.y; acc[6] += w2 * p1.z; acc[7] += w2 * p1.w;
    }
    {   // split 3: parked in out[256:512)
        float4 p0 = *(const float4*)(ob + 256 + dg);
        float4 p1 = *(const float4*)(ob + 256 + dg + 4);
        float w3 = w[3] * invL;
        acc[0] += w3 * p0.x; acc[1] += w3 * p0.y; acc[2] += w3 * p0.z; acc[3] += w3 * p0.w;
        acc[4] += w3 * p1.x; acc[5] += w3 * p1.y; acc[6] += w3 * p1.z; acc[7] += w3 * p1.w;
    }
    float4 d0 = *(const float4*)(dec32 + (size_t)trow * DIM + dg);
    float4 d1 = *(const float4*)(dec32 + (size_t)trow * DIM + dg + 4);
    *(float4*)(ob + dg)     = d0;
    *(float4*)(ob + dg + 4) = d1;
    float4 c0, c1;
    c0.x=acc[0]; c0.y=acc[1]; c0.z=acc[2]; c0.w=acc[3];
    c1.x=acc[4]; c1.y=acc[5]; c1.z=acc[6]; c1.w=acc[7];
    *(float4*)(ob + 256 + dg)     = c0;
    *(float4*)(ob + 256 + dg + 4) = c1;
}

extern "C" void kernel_launch(void* const* d_in, const int* in_sizes, int n_in,
                              void* d_out, int out_size, void* d_ws, size_t ws_size,
                              hipStream_t stream) {
    (void)in_sizes; (void)n_in;
    const float* enc = (const float*)d_in[0];
    const float* dec = (const float*)d_in[1];
    float* out = (float*)d_out;

    const size_t MLB  = (size_t)4 * NBTD * 8;         // 524,288 (f32x2 per split-row)
    const size_t HB   = (size_t)NB * TE * DIM * 2;    // 8,388,608 (ench)
    const size_t C2   = (size_t)2 * NBTD * DIM * 2;   // 16,777,216 (ctxp splits 0,1)
    const size_t NEED = MLB + HB + C2;                // 25,690,112 << proven 33.8 MB

    if (ws_size < NEED) {
        hipMemsetAsync(d_out, 0, (size_t)out_size * sizeof(float), stream);
        return;
    }
    f32x2* ml   = (f32x2*)d_ws;
    f16*   ench = (f16*)((char*)d_ws + MLB);
    f16*   ctxp = (f16*)((char*)d_ws + MLB + HB);

    prep_kernel<<<2048, 256, 0, stream>>>(enc, ench);
    attn_kernel<<<dim3(16, 8, 4), 256, 0, stream>>>(dec, ench, ctxp, ml, out);
    combine_kernel<<<2048, 256, 0, stream>>>(dec, ctxp, ml, out);
}